// Round 3
// baseline (411.183 us; speedup 1.0000x reference)
//
#include <hip/hip_runtime.h>

#define NB 256
#define NT 512
#define NK 128

// tie-aware running argmax update: keep first (smallest-i) max.
// Within a chain we iterate i ascending with strict >, so first max wins.
__device__ __forceinline__ void upd(float v, int i, float& bv, int& bi) {
    bool g = v > bv;
    bv = g ? v : bv;
    bi = g ? i : bi;
}

__global__ __launch_bounds__(256, 1)
void crf_decode_kernel(const float* __restrict__ em,
                       const int* __restrict__ mask,
                       const float* __restrict__ trans,
                       int* __restrict__ out) {
    __shared__ alignas(16) float state_sh[NK];
    __shared__ float part_val[256];
    __shared__ int   part_idx[256];
    __shared__ unsigned char bp_sh[(NT - 1) * NK];   // 65408 B backpointers
    __shared__ int tags_sh[NT];
    __shared__ int len_sh;
    __shared__ int lt_sh;

    const int b    = blockIdx.x;
    const int tid  = threadIdx.x;
    const int j    = tid & (NK - 1);   // output tag index
    const int half = tid >> 7;         // which half of the i-range
    const long base = (long)b * NT * NK;

    // ---- sequence length = sum(mask[b,:]) ----
    int s = mask[b * NT + tid] + mask[b * NT + tid + 256];
    #pragma unroll
    for (int off = 32; off > 0; off >>= 1) s += __shfl_down(s, off, 64);
    if (tid == 0) len_sh = 0;
    __syncthreads();
    if ((tid & 63) == 0) atomicAdd(&len_sh, s);

    // ---- init state = emissions[b,0,:] ----
    if (half == 0) state_sh[j] = em[base + j];

    // ---- transition column chunk in registers (fully static indexing) ----
    float treg[64];
    #pragma unroll
    for (int ii = 0; ii < 64; ++ii)
        treg[ii] = trans[(half * 64 + ii) * NK + j];

    __syncthreads();
    const int len = len_sh;

    // ---- forward Viterbi: only steps t < len change anything ----
    for (int t = 1; t < len; ++t) {
        float e = 0.0f;
        if (half == 0) e = em[base + t * NK + j];   // wave-uniform branch

        float bv0 = -3.4e38f, bv1 = -3.4e38f, bv2 = -3.4e38f, bv3 = -3.4e38f;
        int   bi0 = 0, bi1 = 1, bi2 = 2, bi3 = 3;
        const float4* sp = (const float4*)&state_sh[half * 64];
        #pragma unroll
        for (int g = 0; g < 16; ++g) {
            float4 sv = sp[g];                       // broadcast ds_read_b128
            const int ib = half * 64 + g * 4;
            upd(sv.x + treg[g * 4 + 0], ib + 0, bv0, bi0);
            upd(sv.y + treg[g * 4 + 1], ib + 1, bv1, bi1);
            upd(sv.z + treg[g * 4 + 2], ib + 2, bv2, bi2);
            upd(sv.w + treg[g * 4 + 3], ib + 3, bv3, bi3);
        }
        // tie-aware chain merges (prefer smaller index)
        bool tk;
        tk = (bv1 > bv0) || (bv1 == bv0 && bi1 < bi0);
        float mv0 = tk ? bv1 : bv0; int mi0 = tk ? bi1 : bi0;
        tk = (bv3 > bv2) || (bv3 == bv2 && bi3 < bi2);
        float mv1 = tk ? bv3 : bv2; int mi1 = tk ? bi3 : bi2;
        tk = (mv1 > mv0) || (mv1 == mv0 && mi1 < mi0);
        float bv = tk ? mv1 : mv0;  int bi = tk ? mi1 : mi0;

        part_val[tid] = bv;
        part_idx[tid] = bi;
        __syncthreads();
        if (half == 0) {
            float ov = part_val[tid + 128];
            int   oi = part_idx[tid + 128];
            bool take = ov > bv;          // half1 has larger i -> strict > keeps half0 on tie
            float nv = (take ? ov : bv) + e;
            int   ni = take ? oi : bi;
            state_sh[j] = nv;
            bp_sh[(t - 1) * NK + j] = (unsigned char)ni;
        }
        __syncthreads();
    }

    // ---- last_tag = argmax_j(state) (wave 0, tie-aware) ----
    if (tid < 64) {
        float v0 = state_sh[tid], v1 = state_sh[tid + 64];
        bool take = v1 > v0;               // tie keeps lower index (tid)
        float v = take ? v1 : v0;
        int  ix = take ? tid + 64 : tid;
        #pragma unroll
        for (int off = 32; off > 0; off >>= 1) {
            float vo = __shfl_xor(v, off, 64);
            int   io = __shfl_xor(ix, off, 64);
            bool t2 = (vo > v) || (vo == v && io < ix);
            v  = t2 ? vo : v;
            ix = t2 ? io : ix;
        }
        if (tid == 0) lt_sh = ix;
    }
    __syncthreads();
    const int last_tag = lt_sh;
    const int lm1 = (len > 0) ? (len - 1) : 0;

    // ---- positions p >= len-1 all carry last_tag (parallel fill) ----
    for (int p = tid; p < NT; p += 256)
        if (p >= lm1) tags_sh[p] = last_tag;
    __syncthreads();

    // ---- serial backpointer chase through LDS (p = len-2 .. 0) ----
    if (tid == 0) {
        int tag = last_tag;
        for (int p = lm1 - 1; p >= 0; --p) {
            tag = (int)bp_sh[p * NK + tag];
            tags_sh[p] = tag;
        }
    }
    __syncthreads();

    // ---- apply mask and write int32 output ----
    for (int p = tid; p < NT; p += 256) {
        int mv = mask[b * NT + p];
        out[b * NT + p] = mv ? tags_sh[p] : 0;
    }
}

extern "C" void kernel_launch(void* const* d_in, const int* in_sizes, int n_in,
                              void* d_out, int out_size, void* d_ws, size_t ws_size,
                              hipStream_t stream) {
    const float* em    = (const float*)d_in[0];
    const int*   mask  = (const int*)d_in[1];
    const float* trans = (const float*)d_in[2];
    int* out = (int*)d_out;
    hipLaunchKernelGGL(crf_decode_kernel, dim3(NB), dim3(256), 0, stream,
                       em, mask, trans, out);
}